// Round 1
// baseline (47066.342 us; speedup 1.0000x reference)
//
#include <hip/hip_runtime.h>
#include <math.h>

#define BB 2
#define CIN 8
#define COUTC 8
#define NLAT 128
#define NLON 256
#define EMB 256
#define NLAYERS 4
#define HID 512
#define LMAX 128
#define MMAX 129
#define HW (NLAT*NLON)
#define LM (LMAX*MMAX)

__device__ __forceinline__ float gelu_f(float x) {
    float x3 = x*x*x;
    return 0.5f*x*(1.0f + tanhf(0.7978845608028654f*(x + 0.044715f*x3)));
}

// ---- root table: w[j] = (cos(2*pi*j/256), sin(2*pi*j/256)) ----
__global__ void init_roots_k(float2* __restrict__ roots) {
    int j = threadIdx.x;
    double ang = (6.283185307179586476925286766559 / 256.0) * (double)j;
    roots[j] = make_float2((float)cos(ang), (float)sin(ang));
}

// ---- encoder: h[b,o,p] = b_enc[o] + pos[o,p] + sum_c x[b,c,p]*w_enc[o,c] ----
__global__ void encoder_k(const float* __restrict__ x, const float* __restrict__ w,
                          const float* __restrict__ bias, const float* __restrict__ pos,
                          float* __restrict__ h) {
    int p = blockIdx.x*blockDim.x + threadIdx.x;
    int o = blockIdx.y, b = blockIdx.z;
    float acc = bias[o] + pos[(size_t)o*HW + p];
    const float* xb = x + (size_t)b*CIN*HW + p;
    const float* wo = w + o*CIN;
    #pragma unroll
    for (int c = 0; c < CIN; ++c) acc += xb[(size_t)c*HW]*wo[c];
    h[((size_t)b*EMB + o)*HW + p] = acc;
}

// ---- rfft (direct DFT): xf[row,m] = (2pi/256) * sum_n h[row,n] e^{-2pi i n m /256} ----
__global__ void rfft_k(const float* __restrict__ h, float2* __restrict__ xf,
                       const float2* __restrict__ roots) {
    __shared__ float  lh[NLON];
    __shared__ float2 lw[NLON];
    int row = blockIdx.x; int tid = threadIdx.x;  // block = 128
    lh[tid]       = h[(size_t)row*NLON + tid];
    lh[tid + 128] = h[(size_t)row*NLON + tid + 128];
    lw[tid] = roots[tid]; lw[tid + 128] = roots[tid + 128];
    __syncthreads();
    const float S = (float)(6.283185307179586476925286766559 / 256.0);
    for (int m = tid; m < MMAX; m += 128) {   // tid 0 also does m=128
        float re = 0.f, im = 0.f;
        for (int n = 0; n < NLON; ++n) {
            int j = (n*m) & 255;
            float v = lh[n];
            re += v*lw[j].x;
            im -= v*lw[j].y;
        }
        xf[(size_t)row*MMAX + m] = make_float2(re*S, im*S);
    }
}

// ---- Legendre SHT: hs[bc,l,m] = sum_k sht_wt[m,l,k] * xf[bc,k,m] ----
__global__ void sht_leg_k(const float2* __restrict__ xf, const float* __restrict__ wt,
                          float2* __restrict__ hs) {
    long idx = (long)blockIdx.x*blockDim.x + threadIdx.x;
    if (idx >= (long)BB*EMB*LMAX*MMAX) return;
    int m  = (int)(idx % MMAX);
    long r = idx / MMAX;
    int l  = (int)(r % LMAX);
    int bc = (int)(r / LMAX);
    const float2* xr = xf + (size_t)bc*NLAT*MMAX + m;
    const float*  wr = wt + ((size_t)m*LMAX + l)*NLAT;
    float re = 0.f, im = 0.f;
    for (int k = 0; k < NLAT; ++k) {
        float2 v = xr[(size_t)k*MMAX];
        float  w = wr[k];
        re += w*v.x; im += w*v.y;
    }
    hs[((size_t)bc*LMAX + l)*MMAX + m] = make_float2(re, im);
}

// ---- dhconv: out[b,o,l,m] = sum_i hs[b,i,l,m] * wc[i,o,l]  (complex) ----
__global__ void dhconv_k(const float2* __restrict__ hs, const float* __restrict__ spec,
                         float2* __restrict__ out) {
    int lm = blockIdx.x*blockDim.x + threadIdx.x;
    if (lm >= LM) return;
    int l  = lm / MMAX;
    int o0 = blockIdx.y*8;
    int b  = blockIdx.z;
    float2 acc[8];
    #pragma unroll
    for (int j = 0; j < 8; ++j) acc[j] = make_float2(0.f, 0.f);
    const float2* hrow = hs + (size_t)b*EMB*LM + lm;
    const float2* ws   = (const float2*)spec + l;   // spec[(i*EMB+o)*LMAX+l] complex
    for (int i = 0; i < EMB; ++i) {
        float2 v = hrow[(size_t)i*LM];
        const float2* wrow = ws + ((size_t)i*EMB + o0)*LMAX;
        #pragma unroll
        for (int j = 0; j < 8; ++j) {
            float2 w = wrow[(size_t)j*LMAX];
            acc[j].x += v.x*w.x - v.y*w.y;
            acc[j].y += v.x*w.y + v.y*w.x;
        }
    }
    float2* orow = out + (size_t)b*EMB*LM + lm;
    #pragma unroll
    for (int j = 0; j < 8; ++j) orow[(size_t)(o0 + j)*LM] = acc[j];
}

// ---- Legendre ISHT: y[bc,k,m] = sum_l hs[bc,l,m] * isht_wt[m,l,k] ----
__global__ void isht_leg_k(const float2* __restrict__ hs, const float* __restrict__ wt,
                           float2* __restrict__ y) {
    long idx = (long)blockIdx.x*blockDim.x + threadIdx.x;
    if (idx >= (long)BB*EMB*NLAT*MMAX) return;
    int m  = (int)(idx % MMAX);
    long r = idx / MMAX;
    int k  = (int)(r % NLAT);
    int bc = (int)(r / NLAT);
    const float2* hrow = hs + (size_t)bc*LMAX*MMAX + m;
    const float*  wc   = wt + (size_t)m*LMAX*NLAT + k;
    float re = 0.f, im = 0.f;
    for (int l = 0; l < LMAX; ++l) {
        float2 v = hrow[(size_t)l*MMAX];
        float  w = wc[(size_t)l*NLAT];
        re += w*v.x; im += w*v.y;
    }
    y[((size_t)bc*NLAT + k)*MMAX + m] = make_float2(re, im);
}

// ---- irfft + gelu + residual(in place on h) ----
// x[n] = Y0.re + (-1)^n Y128.re + 2*sum_{m=1..127}(Y.re cos - Y.im sin);  h = gelu(x)+h
__global__ void irfft_gelu_res_k(const float2* __restrict__ y, float* __restrict__ h,
                                 const float2* __restrict__ roots) {
    __shared__ float2 ly[MMAX];
    __shared__ float2 lw[NLON];
    int row = blockIdx.x; int n = threadIdx.x;   // block = 256
    if (n < MMAX) ly[n] = y[(size_t)row*MMAX + n];
    lw[n] = roots[n];
    __syncthreads();
    float acc = ly[0].x + ((n & 1) ? -ly[128].x : ly[128].x);
    float acc2 = 0.f;
    for (int m = 1; m < 128; ++m) {
        int j = (n*m) & 255;
        float2 w = lw[j];
        float2 v = ly[m];
        acc2 += v.x*w.x - v.y*w.y;
    }
    acc += 2.f*acc2;
    size_t gi = (size_t)row*NLON + n;
    h[gi] = gelu_f(acc) + h[gi];
}

// ---- MLP1: t[b,d,p] = gelu(b1[d] + sum_c h[b,c,p]*w1[d,c]) ----
__global__ void mlp1_k(const float* __restrict__ h, const float* __restrict__ w1,
                       const float* __restrict__ b1, float* __restrict__ t) {
    int p  = blockIdx.x*blockDim.x + threadIdx.x;
    int d0 = blockIdx.y*8;
    int b  = blockIdx.z;
    float acc[8];
    #pragma unroll
    for (int j = 0; j < 8; ++j) acc[j] = b1[d0 + j];
    const float* hb = h + (size_t)b*EMB*HW + p;
    const float* w  = w1 + (size_t)d0*EMB;
    for (int c = 0; c < EMB; ++c) {
        float hv = hb[(size_t)c*HW];
        #pragma unroll
        for (int j = 0; j < 8; ++j) acc[j] += hv * w[(size_t)j*EMB + c];
    }
    float* tb = t + (size_t)b*HID*HW + (size_t)d0*HW + p;
    #pragma unroll
    for (int j = 0; j < 8; ++j) tb[(size_t)j*HW] = gelu_f(acc[j]);
}

// ---- MLP2 + residual(in place): h[b,c,p] = h[b,c,p] + b2[c] + sum_d t[b,d,p]*w2[c,d] ----
__global__ void mlp2_k(const float* __restrict__ t, const float* __restrict__ w2,
                       const float* __restrict__ b2, float* __restrict__ h) {
    int p  = blockIdx.x*blockDim.x + threadIdx.x;
    int c0 = blockIdx.y*8;
    int b  = blockIdx.z;
    float acc[8];
    #pragma unroll
    for (int j = 0; j < 8; ++j) acc[j] = b2[c0 + j];
    const float* tb = t + (size_t)b*HID*HW + p;
    const float* w  = w2 + (size_t)c0*HID;
    for (int d = 0; d < HID; ++d) {
        float tv = tb[(size_t)d*HW];
        #pragma unroll
        for (int j = 0; j < 8; ++j) acc[j] += tv * w[(size_t)j*HID + d];
    }
    float* hb = h + (size_t)b*EMB*HW + (size_t)c0*HW + p;
    #pragma unroll
    for (int j = 0; j < 8; ++j) hb[(size_t)j*HW] = acc[j] + hb[(size_t)j*HW];
}

// ---- decoder: out[b,o,p] = b_dec[o] + sum_c h[b,c,p]*w_dec[o,c] ----
__global__ void decoder_k(const float* __restrict__ h, const float* __restrict__ w,
                          const float* __restrict__ bias, float* __restrict__ out) {
    int p = blockIdx.x*blockDim.x + threadIdx.x;
    int b = blockIdx.y;
    float acc[COUTC];
    #pragma unroll
    for (int o = 0; o < COUTC; ++o) acc[o] = bias[o];
    const float* hb = h + (size_t)b*EMB*HW + p;
    for (int c = 0; c < EMB; ++c) {
        float hv = hb[(size_t)c*HW];
        #pragma unroll
        for (int o = 0; o < COUTC; ++o) acc[o] += hv * w[o*EMB + c];
    }
    #pragma unroll
    for (int o = 0; o < COUTC; ++o) out[((size_t)b*COUTC + o)*HW + p] = acc[o];
}

extern "C" void kernel_launch(void* const* d_in, const int* in_sizes, int n_in,
                              void* d_out, int out_size, void* d_ws, size_t ws_size,
                              hipStream_t stream) {
    const float* x        = (const float*)d_in[0];
    const float* w_enc    = (const float*)d_in[1];
    const float* b_enc    = (const float*)d_in[2];
    const float* pos      = (const float*)d_in[3];
    const float* spec_w   = (const float*)d_in[4];
    const float* w1       = (const float*)d_in[5];
    const float* b1       = (const float*)d_in[6];
    const float* w2       = (const float*)d_in[7];
    const float* b2       = (const float*)d_in[8];
    const float* w_dec    = (const float*)d_in[9];
    const float* b_dec    = (const float*)d_in[10];
    const float* sht_wt   = (const float*)d_in[11];
    const float* isht_wt  = (const float*)d_in[12];
    float* out = (float*)d_out;

    float* ws = (float*)d_ws;
    float* h  = ws;                                    // B*EMB*HW      = 16777216
    float* t  = h + (size_t)BB*EMB*HW;                 // B*HID*HW      = 33554432
    float* A  = t + (size_t)BB*HID*HW;                 // B*EMB*L*M*2   = 16908288
    float* Bb = A + (size_t)BB*EMB*LMAX*MMAX*2;        // B*EMB*L*M*2   = 16908288
    float2* roots = (float2*)(Bb + (size_t)BB*EMB*LMAX*MMAX*2);  // 256 float2

    hipLaunchKernelGGL(init_roots_k, dim3(1), dim3(256), 0, stream, roots);
    hipLaunchKernelGGL(encoder_k, dim3(HW/256, EMB, BB), dim3(256), 0, stream,
                       x, w_enc, b_enc, pos, h);
    for (int l = 0; l < NLAYERS; ++l) {
        const float* spec_l = spec_w + (size_t)l*EMB*EMB*LMAX*2;
        hipLaunchKernelGGL(rfft_k, dim3(BB*EMB*NLAT), dim3(128), 0, stream,
                           h, (float2*)A, roots);
        hipLaunchKernelGGL(sht_leg_k, dim3((BB*EMB*LMAX*MMAX + 255)/256), dim3(256), 0, stream,
                           (const float2*)A, sht_wt, (float2*)Bb);
        hipLaunchKernelGGL(dhconv_k, dim3((LM + 255)/256, EMB/8, BB), dim3(256), 0, stream,
                           (const float2*)Bb, spec_l, (float2*)A);
        hipLaunchKernelGGL(isht_leg_k, dim3((BB*EMB*NLAT*MMAX + 255)/256), dim3(256), 0, stream,
                           (const float2*)A, isht_wt, (float2*)Bb);
        hipLaunchKernelGGL(irfft_gelu_res_k, dim3(BB*EMB*NLAT), dim3(256), 0, stream,
                           (const float2*)Bb, h, roots);
        hipLaunchKernelGGL(mlp1_k, dim3(HW/256, HID/8, BB), dim3(256), 0, stream,
                           h, w1 + (size_t)l*HID*EMB, b1 + (size_t)l*HID, t);
        hipLaunchKernelGGL(mlp2_k, dim3(HW/256, EMB/8, BB), dim3(256), 0, stream,
                           t, w2 + (size_t)l*EMB*HID, b2 + (size_t)l*EMB, h);
    }
    hipLaunchKernelGGL(decoder_k, dim3(HW/256, BB), dim3(256), 0, stream,
                       h, w_dec, b_dec, out);
}

// Round 2
// 11636.501 us; speedup vs baseline: 4.0447x; 4.0447x over previous
//
#include <hip/hip_runtime.h>
#include <math.h>

#define BB 2
#define CIN 8
#define COUTC 8
#define NLAT 128
#define NLON 256
#define EMB 256
#define NLAYERS 4
#define HID 512
#define LMAX 128
#define MMAX 129
#define HW (NLAT*NLON)
#define ML (MMAX*LMAX)   // spectral plane size per channel (m-major, l contiguous)

__device__ __forceinline__ float gelu_f(float x) {
    float x3 = x*x*x;
    return 0.5f*x*(1.0f + tanhf(0.7978845608028654f*(x + 0.044715f*x3)));
}

// ---- root table: w[j] = (cos(2*pi*j/256), sin(2*pi*j/256)) ----
__global__ void init_roots_k(float2* __restrict__ roots) {
    int j = threadIdx.x;
    double ang = (6.283185307179586476925286766559 / 256.0) * (double)j;
    roots[j] = make_float2((float)cos(ang), (float)sin(ang));
}

// ---- encoder: h[b,o,p] = b_enc[o] + pos[o,p] + sum_c x[b,c,p]*w_enc[o,c] ----
__global__ void encoder_k(const float* __restrict__ x, const float* __restrict__ w,
                          const float* __restrict__ bias, const float* __restrict__ pos,
                          float* __restrict__ h) {
    int p = blockIdx.x*blockDim.x + threadIdx.x;
    int o = blockIdx.y, b = blockIdx.z;
    float acc = bias[o] + pos[(size_t)o*HW + p];
    const float* xb = x + (size_t)b*CIN*HW + p;
    const float* wo = w + o*CIN;
    #pragma unroll
    for (int c = 0; c < CIN; ++c) acc += xb[(size_t)c*HW]*wo[c];
    h[((size_t)b*EMB + o)*HW + p] = acc;
}

// ---- rfft (direct DFT): xf[bc][m][k] = (2pi/256) * sum_n h[bc,k,n] e^{-2pi i n m /256} ----
__global__ void rfft_k(const float* __restrict__ h, float2* __restrict__ xf,
                       const float2* __restrict__ roots) {
    __shared__ float  lh[NLON];
    __shared__ float2 lw[NLON];
    int row = blockIdx.x; int tid = threadIdx.x;  // block = 128
    int bc = row >> 7, k = row & 127;
    lh[tid]       = h[(size_t)row*NLON + tid];
    lh[tid + 128] = h[(size_t)row*NLON + tid + 128];
    lw[tid] = roots[tid]; lw[tid + 128] = roots[tid + 128];
    __syncthreads();
    const float S = (float)(6.283185307179586476925286766559 / 256.0);
    for (int m = tid; m < MMAX; m += 128) {   // tid 0 also does m=128
        float re = 0.f, im = 0.f;
        for (int n = 0; n < NLON; ++n) {
            int j = (n*m) & 255;
            float v = lh[n];
            re += v*lw[j].x;
            im -= v*lw[j].y;
        }
        xf[((size_t)bc*MMAX + m)*NLAT + k] = make_float2(re*S, im*S);
    }
}

// ---- Legendre SHT (LDS-tiled): hs[bc][m][l] = sum_k wt[m,l,k] * xf[bc][m][k] ----
// block = (m, bc-tile of 32), 256 threads; thread owns l = t&127, handles 16 bc rows.
__global__ void sht_leg_k(const float* __restrict__ xf, const float* __restrict__ wt,
                          float* __restrict__ hs) {
    __shared__ float xs[32][64];     // [bc_local][2*k_local]  8 KB
    __shared__ float ws[32][128];    // [k_local][l]          16 KB
    int m = blockIdx.x;
    int bc0 = blockIdx.y * 32;
    int t = threadIdx.x;
    int l = t & 127, sub = t >> 7;   // sub in {0,1}
    float2 acc[16];
    #pragma unroll
    for (int j = 0; j < 16; ++j) acc[j] = make_float2(0.f, 0.f);
    int r = t >> 3, c = (t & 7) * 8;           // staging coords for xs
    for (int kc = 0; kc < NLAT; kc += 32) {
        // stage xf chunk: 32 bc-rows x 32 k (complex) -> 2048 floats
        const float* src = xf + (((size_t)(bc0 + r)*MMAX + m)*NLAT + kc)*2 + c;
        *(float4*)&xs[r][c]     = *(const float4*)src;
        *(float4*)&xs[r][c + 4] = *(const float4*)(src + 4);
        // stage wt chunk transposed: ws[kk][l], each thread loads 16 contiguous k
        const float* wsrc = wt + ((size_t)m*LMAX + l)*NLAT + kc + sub*16;
        #pragma unroll
        for (int q = 0; q < 16; ++q) ws[sub*16 + q][l] = wsrc[q];
        __syncthreads();
        #pragma unroll 4
        for (int kk = 0; kk < 32; ++kk) {
            float w = ws[kk][l];
            #pragma unroll
            for (int j = 0; j < 16; ++j) {
                float xr = xs[sub*16 + j][2*kk];
                float xi = xs[sub*16 + j][2*kk + 1];
                acc[j].x += w * xr;
                acc[j].y += w * xi;
            }
        }
        __syncthreads();
    }
    #pragma unroll
    for (int j = 0; j < 16; ++j) {
        int bc = bc0 + sub*16 + j;
        ((float2*)hs)[((size_t)bc*MMAX + m)*LMAX + l] = acc[j];
    }
}

// ---- dhconv: out[b,o,m,l] = sum_i hs[b,i,m,l] * wc[i,o,l]  (complex, l contiguous) ----
__global__ void dhconv_k(const float2* __restrict__ hs, const float* __restrict__ spec,
                         float2* __restrict__ out) {
    int pos = blockIdx.x*blockDim.x + threadIdx.x;  // over ML (m-major, l contiguous)
    if (pos >= ML) return;
    int l  = pos & 127;
    int o0 = blockIdx.y*8;
    int b  = blockIdx.z;
    float2 acc[8];
    #pragma unroll
    for (int j = 0; j < 8; ++j) acc[j] = make_float2(0.f, 0.f);
    const float2* hrow = hs + (size_t)b*EMB*ML + pos;
    const float2* wbase = (const float2*)spec + l;   // spec[(i*EMB+o)*LMAX+l] complex
    for (int i = 0; i < EMB; ++i) {
        float2 v = hrow[(size_t)i*ML];
        const float2* wrow = wbase + ((size_t)i*EMB + o0)*LMAX;
        #pragma unroll
        for (int j = 0; j < 8; ++j) {
            float2 w = wrow[(size_t)j*LMAX];
            acc[j].x += v.x*w.x - v.y*w.y;
            acc[j].y += v.x*w.y + v.y*w.x;
        }
    }
    float2* orow = out + (size_t)b*EMB*ML + pos;
    #pragma unroll
    for (int j = 0; j < 8; ++j) orow[(size_t)(o0 + j)*ML] = acc[j];
}

// ---- Legendre ISHT (LDS-tiled): y[bc][m][k] = sum_l wt[m,l,k] * hs[bc][m][l] ----
// block = (m, bc-tile of 32), 256 threads; thread owns k = t&127, handles 16 bc rows.
__global__ void isht_leg_k(const float* __restrict__ hs, const float* __restrict__ wt,
                           float* __restrict__ y) {
    __shared__ float hss[32][64];     // [bc_local][2*l_local]  8 KB
    __shared__ float ws[32][132];     // [l_local][k] +4 pad   16.5 KB
    int m = blockIdx.x;
    int bc0 = blockIdx.y * 32;
    int t = threadIdx.x;
    int k = t & 127, sub = t >> 7;
    float2 acc[16];
    #pragma unroll
    for (int j = 0; j < 16; ++j) acc[j] = make_float2(0.f, 0.f);
    int r = t >> 3, c = (t & 7) * 8;
    int lr = t >> 3, c2 = (t & 7) * 16;       // wt staging: 8 threads per l-row
    for (int lc = 0; lc < LMAX; lc += 32) {
        const float* src = hs + (((size_t)(bc0 + r)*MMAX + m)*LMAX + lc)*2 + c;
        *(float4*)&hss[r][c]     = *(const float4*)src;
        *(float4*)&hss[r][c + 4] = *(const float4*)(src + 4);
        const float* wsrc = wt + ((size_t)m*LMAX + lc + lr)*NLAT + c2;
        *(float4*)&ws[lr][c2]      = *(const float4*)wsrc;
        *(float4*)&ws[lr][c2 + 4]  = *(const float4*)(wsrc + 4);
        *(float4*)&ws[lr][c2 + 8]  = *(const float4*)(wsrc + 8);
        *(float4*)&ws[lr][c2 + 12] = *(const float4*)(wsrc + 12);
        __syncthreads();
        #pragma unroll 4
        for (int lk = 0; lk < 32; ++lk) {
            float w = ws[lk][k];
            #pragma unroll
            for (int j = 0; j < 16; ++j) {
                float hr = hss[sub*16 + j][2*lk];
                float hi = hss[sub*16 + j][2*lk + 1];
                acc[j].x += w * hr;
                acc[j].y += w * hi;
            }
        }
        __syncthreads();
    }
    #pragma unroll
    for (int j = 0; j < 16; ++j) {
        int bc = bc0 + sub*16 + j;
        ((float2*)y)[((size_t)bc*MMAX + m)*NLAT + k] = acc[j];
    }
}

// ---- irfft + gelu + residual(in place on h); y layout [bc][m][k] ----
__global__ void irfft_gelu_res_k(const float2* __restrict__ y, float* __restrict__ h,
                                 const float2* __restrict__ roots) {
    __shared__ float2 ly[MMAX];
    __shared__ float2 lw[NLON];
    int row = blockIdx.x; int n = threadIdx.x;   // block = 256
    int bc = row >> 7, k = row & 127;
    if (n < MMAX) ly[n] = y[((size_t)bc*MMAX + n)*NLAT + k];
    lw[n] = roots[n];
    __syncthreads();
    float acc = ly[0].x + ((n & 1) ? -ly[128].x : ly[128].x);
    float acc2 = 0.f;
    for (int m = 1; m < 128; ++m) {
        int j = (n*m) & 255;
        float2 w = lw[j];
        float2 v = ly[m];
        acc2 += v.x*w.x - v.y*w.y;
    }
    acc += 2.f*acc2;
    size_t gi = (size_t)row*NLON + n;
    h[gi] = gelu_f(acc) + h[gi];
}

// ---- MLP1: t[b,d,p] = gelu(b1[d] + sum_c h[b,c,p]*w1[d,c]) ----
__global__ void mlp1_k(const float* __restrict__ h, const float* __restrict__ w1,
                       const float* __restrict__ b1, float* __restrict__ t) {
    int p  = blockIdx.x*blockDim.x + threadIdx.x;
    int d0 = blockIdx.y*8;
    int b  = blockIdx.z;
    float acc[8];
    #pragma unroll
    for (int j = 0; j < 8; ++j) acc[j] = b1[d0 + j];
    const float* hb = h + (size_t)b*EMB*HW + p;
    const float* w  = w1 + (size_t)d0*EMB;
    for (int c = 0; c < EMB; ++c) {
        float hv = hb[(size_t)c*HW];
        #pragma unroll
        for (int j = 0; j < 8; ++j) acc[j] += hv * w[(size_t)j*EMB + c];
    }
    float* tb = t + (size_t)b*HID*HW + (size_t)d0*HW + p;
    #pragma unroll
    for (int j = 0; j < 8; ++j) tb[(size_t)j*HW] = gelu_f(acc[j]);
}

// ---- MLP2 + residual(in place): h[b,c,p] += b2[c] + sum_d t[b,d,p]*w2[c,d] ----
__global__ void mlp2_k(const float* __restrict__ t, const float* __restrict__ w2,
                       const float* __restrict__ b2, float* __restrict__ h) {
    int p  = blockIdx.x*blockDim.x + threadIdx.x;
    int c0 = blockIdx.y*8;
    int b  = blockIdx.z;
    float acc[8];
    #pragma unroll
    for (int j = 0; j < 8; ++j) acc[j] = b2[c0 + j];
    const float* tb = t + (size_t)b*HID*HW + p;
    const float* w  = w2 + (size_t)c0*HID;
    for (int d = 0; d < HID; ++d) {
        float tv = tb[(size_t)d*HW];
        #pragma unroll
        for (int j = 0; j < 8; ++j) acc[j] += tv * w[(size_t)j*HID + d];
    }
    float* hb = h + (size_t)b*EMB*HW + (size_t)c0*HW + p;
    #pragma unroll
    for (int j = 0; j < 8; ++j) hb[(size_t)j*HW] = acc[j] + hb[(size_t)j*HW];
}

// ---- decoder: out[b,o,p] = b_dec[o] + sum_c h[b,c,p]*w_dec[o,c] ----
__global__ void decoder_k(const float* __restrict__ h, const float* __restrict__ w,
                          const float* __restrict__ bias, float* __restrict__ out) {
    int p = blockIdx.x*blockDim.x + threadIdx.x;
    int b = blockIdx.y;
    float acc[COUTC];
    #pragma unroll
    for (int o = 0; o < COUTC; ++o) acc[o] = bias[o];
    const float* hb = h + (size_t)b*EMB*HW + p;
    for (int c = 0; c < EMB; ++c) {
        float hv = hb[(size_t)c*HW];
        #pragma unroll
        for (int o = 0; o < COUTC; ++o) acc[o] += hv * w[o*EMB + c];
    }
    #pragma unroll
    for (int o = 0; o < COUTC; ++o) out[((size_t)b*COUTC + o)*HW + p] = acc[o];
}

extern "C" void kernel_launch(void* const* d_in, const int* in_sizes, int n_in,
                              void* d_out, int out_size, void* d_ws, size_t ws_size,
                              hipStream_t stream) {
    const float* x        = (const float*)d_in[0];
    const float* w_enc    = (const float*)d_in[1];
    const float* b_enc    = (const float*)d_in[2];
    const float* pos      = (const float*)d_in[3];
    const float* spec_w   = (const float*)d_in[4];
    const float* w1       = (const float*)d_in[5];
    const float* b1       = (const float*)d_in[6];
    const float* w2       = (const float*)d_in[7];
    const float* b2       = (const float*)d_in[8];
    const float* w_dec    = (const float*)d_in[9];
    const float* b_dec    = (const float*)d_in[10];
    const float* sht_wt   = (const float*)d_in[11];
    const float* isht_wt  = (const float*)d_in[12];
    float* out = (float*)d_out;

    float* ws = (float*)d_ws;
    float* h  = ws;                                    // B*EMB*HW      = 16777216
    float* t  = h + (size_t)BB*EMB*HW;                 // B*HID*HW      = 33554432
    float* A  = t + (size_t)BB*HID*HW;                 // B*EMB*M*K*2   = 16908288
    float* Bb = A + (size_t)BB*EMB*MMAX*NLAT*2;        // B*EMB*M*L*2   = 16908288
    float2* roots = (float2*)(Bb + (size_t)BB*EMB*MMAX*LMAX*2);  // 256 float2

    hipLaunchKernelGGL(init_roots_k, dim3(1), dim3(256), 0, stream, roots);
    hipLaunchKernelGGL(encoder_k, dim3(HW/256, EMB, BB), dim3(256), 0, stream,
                       x, w_enc, b_enc, pos, h);
    for (int l = 0; l < NLAYERS; ++l) {
        const float* spec_l = spec_w + (size_t)l*EMB*EMB*LMAX*2;
        hipLaunchKernelGGL(rfft_k, dim3(BB*EMB*NLAT), dim3(128), 0, stream,
                           h, (float2*)A, roots);
        hipLaunchKernelGGL(sht_leg_k, dim3(MMAX, (BB*EMB)/32), dim3(256), 0, stream,
                           A, sht_wt, Bb);
        hipLaunchKernelGGL(dhconv_k, dim3((ML + 255)/256, EMB/8, BB), dim3(256), 0, stream,
                           (const float2*)Bb, spec_l, (float2*)A);
        hipLaunchKernelGGL(isht_leg_k, dim3(MMAX, (BB*EMB)/32), dim3(256), 0, stream,
                           A, isht_wt, Bb);
        hipLaunchKernelGGL(irfft_gelu_res_k, dim3(BB*EMB*NLAT), dim3(256), 0, stream,
                           (const float2*)Bb, h, roots);
        hipLaunchKernelGGL(mlp1_k, dim3(HW/256, HID/8, BB), dim3(256), 0, stream,
                           h, w1 + (size_t)l*HID*EMB, b1 + (size_t)l*HID, t);
        hipLaunchKernelGGL(mlp2_k, dim3(HW/256, EMB/8, BB), dim3(256), 0, stream,
                           t, w2 + (size_t)l*EMB*HID, b2 + (size_t)l*EMB, h);
    }
    hipLaunchKernelGGL(decoder_k, dim3(HW/256, BB), dim3(256), 0, stream,
                       h, w_dec, b_dec, out);
}